// Round 5
// baseline (229.910 us; speedup 1.0000x reference)
//
#include <hip/hip_runtime.h>
#include <hip/hip_fp16.h>
#include <stdint.h>

// AQT int8 MLP: M=8192, C=1024, H=4096. All I/O float32.
// Exact path: fake_quant values are q/s (integer q), so xq@wq is exact in int32 MFMA.
// 4 dispatches: stats -> quant(x,W1t,W2t) -> GEMM1(h fp16-frag + block hmax)
//            -> GEMM2 (fused: hmax reduce + packed magic-quant of h + GEMM + bias).
//
// int8 operands in MFMA-FRAGMENT ORDER: frag = 1KB = 32 rows x 32 k;
//   byte lane*16+j <-> (row=lane&31, k=(lane>>5)*16+j); frag id = rowblk*(K/32)+kblk.
// h stored fp16 in fragment order: frag = 2KB; halfword ((k>>4)*32+r)*16+(k&15),
//   so GEMM2 staging lane l reads one contiguous 32B at frag*2048 + l*32.
// Magic quant: fp32 fma(x,s,1.5*2^23) -> low byte = int8 q (two's complement);
//   fp16 hfma2(h,s,1536) -> low byte of each half = q (h>=0 after relu).
//
// Round-4 postmortem: both GEMMs plateau at ~25-28% MfmaUtil with NO saturated
// pipe (LDS 36%, L2 ~40%, HBM 19%) -> 2-phase sync-structure stall (m233).
// GEMM2 now uses a phase-split schedule (T3+T4+T5): per K-step two phases
// {barrier -> ds_read one kc -> stage-issue -> lgkmcnt(0) -> setprio MFMA x4},
// 4-deep LDS buffer ring (64KB), A quant written 2 steps ahead, B DMA 2 steps
// ahead; NO steady-state vmcnt drain (B retirement transitively guaranteed by
// the compiler's in-order vmcnt wait on younger A-prefetch registers).
// GEMM1 unchanged this round (isolate the change).

#define EPSQ 1e-6f
typedef int v4i __attribute__((ext_vector_type(4)));
typedef int v16i __attribute__((ext_vector_type(16)));

__device__ __forceinline__ void async16(const int8_t* g, int8_t* l) {
  __builtin_amdgcn_global_load_lds(
      (const __attribute__((address_space(1))) void*)g,
      (__attribute__((address_space(3))) void*)l, 16, 0, 0);
}
__device__ __forceinline__ unsigned short f2h(float f) {
  __half h = __float2half(f);
  return *(unsigned short*)&h;
}
__device__ __forceinline__ float4 max4(float4 m, float4 v) {
  m.x = fmaxf(m.x, fabsf(v.x)); m.y = fmaxf(m.y, fabsf(v.y));
  m.z = fmaxf(m.z, fabsf(v.z)); m.w = fmaxf(m.w, fabsf(v.w));
  return m;
}
// fp32 magic quant: |x*s| <= 127 guaranteed by construction (s = 127/absmax).
__device__ __forceinline__ unsigned qmb(float x, float s) {
  return __float_as_uint(fmaf(x, s, 12582912.0f)) & 0xffu;   // 1.5*2^23
}
__device__ __forceinline__ unsigned q4f(float4 f, float s) {
  return qmb(f.x, s) | (qmb(f.y, s) << 8) | (qmb(f.z, s) << 16) |
         (__float_as_uint(fmaf(f.w, s, 12582912.0f)) << 24);
}
// fp16 packed magic quant: two halfs -> ... -> select low bytes of 4 halfs.
__device__ __forceinline__ unsigned q4h(unsigned ua, unsigned ub,
                                        __half2 s2, __half2 m2) {
  __half2 ha = __hfma2(*(__half2*)&ua, s2, m2);
  __half2 hb = __hfma2(*(__half2*)&ub, s2, m2);
  unsigned va = *(unsigned*)&ha, vb = *(unsigned*)&hb;
#if __has_builtin(__builtin_amdgcn_perm)
  return __builtin_amdgcn_perm(vb, va, 0x06040200u);
#else
  return (va & 0xffu) | ((va >> 8) & 0xff00u) |
         ((vb & 0xffu) << 16) | (((vb >> 8) & 0xff00u) << 16);
#endif
}

// ===== dispatch 1: stats. W1: 16 rowsplits x 4 colgroups; W2: 64 rowsplits;
// x masked absmax: 1024 blk. =====
__global__ __launch_bounds__(256) void k_stats(
    const float* __restrict__ x, const float* __restrict__ mask,
    const float* __restrict__ W1, const float* __restrict__ W2,
    float* __restrict__ pmaxX, float* __restrict__ pcm1, float* __restrict__ pcm2) {
  const int bx = blockIdx.x, tid = threadIdx.x;
  if (bx < 64) {                       // W1 [1024,4096]
    const int sp = bx & 15, cg = bx >> 4;
    const int col = cg * 1024 + tid * 4;
    float4 m = {0.f, 0.f, 0.f, 0.f};
#pragma unroll 8
    for (int r = 0; r < 64; ++r)
      m = max4(m, *(const float4*)(W1 + (size_t)(sp * 64 + r) * 4096 + col));
    *(float4*)(pcm1 + sp * 4096 + col) = m;
  } else if (bx < 128) {               // W2 [4096,1024]
    const int sp = bx - 64;
    const int col = tid * 4;
    float4 m = {0.f, 0.f, 0.f, 0.f};
#pragma unroll 8
    for (int r = 0; r < 64; ++r)
      m = max4(m, *(const float4*)(W2 + (size_t)(sp * 64 + r) * 1024 + col));
    *(float4*)(pcm2 + sp * 1024 + col) = m;
  } else {                             // masked absmax of x -> per-block partial
    __shared__ float red[4];
    const int b = bx - 128;            // 1024 blocks
    float lmax = 0.f;
    for (int c = b * 256 + tid; c < 1048576; c += 262144) {
      size_t idx = (size_t)c * 8;
      float mk = fabsf(mask[idx >> 10]);
      float4 m4 = {0.f, 0.f, 0.f, 0.f};
      m4 = max4(m4, *(const float4*)(x + idx));
      m4 = max4(m4, *(const float4*)(x + idx + 4));
      lmax = fmaxf(lmax, fmaxf(fmaxf(m4.x, m4.y), fmaxf(m4.z, m4.w)) * mk);
    }
    for (int s = 32; s; s >>= 1) lmax = fmaxf(lmax, __shfl_down(lmax, s));
    if ((tid & 63) == 0) red[tid >> 6] = lmax;
    __syncthreads();
    if (tid == 0)
      pmaxX[b] = fmaxf(fmaxf(red[0], red[1]), fmaxf(red[2], red[3]));
  }
}

// ===== dispatch 2: quantize x (2048 blk, frag order), W1->qW1t (256), W2->qW2t (256)
__global__ __launch_bounds__(256) void k_quant(
    const float* __restrict__ x, const float* __restrict__ W1, const float* __restrict__ W2,
    const float* __restrict__ pmaxX, const float* __restrict__ pcm1, const float* __restrict__ pcm2,
    int8_t* __restrict__ qx, int8_t* __restrict__ qw1, int8_t* __restrict__ qw2,
    float* __restrict__ cm1, float* __restrict__ cm2, float* __restrict__ scG) {
  const int bx = blockIdx.x, tid = threadIdx.x;
  if (bx < 2048) {                     // x [8192,1024] -> qx frag order
    __shared__ float red[4];
    float v = fmaxf(fmaxf(pmaxX[tid], pmaxX[tid + 256]),
                    fmaxf(pmaxX[tid + 512], pmaxX[tid + 768]));
    for (int s = 32; s; s >>= 1) v = fmaxf(v, __shfl_down(v, s));
    if ((tid & 63) == 0) red[tid >> 6] = v;
    __syncthreads();
    const float xmax = fmaxf(fmaxf(red[0], red[1]), fmaxf(red[2], red[3]));
    if (bx == 0 && tid == 0) scG[0] = xmax;
    const float s = 127.0f / fmaxf(xmax, EPSQ);
    const int wave = tid >> 6, lane = tid & 63;
    const int f = bx * 4 + wave;                   // frag id; Kf = 1024/32 = 32
    const int r = (f >> 5) * 32 + (lane & 31);
    const int k = (f & 31) * 32 + (lane >> 5) * 16;
    const float4* src = (const float4*)(x + (size_t)r * 1024 + k);
    uint4 o;
    o.x = q4f(src[0], s); o.y = q4f(src[1], s);
    o.z = q4f(src[2], s); o.w = q4f(src[3], s);
    *(uint4*)(qx + (size_t)f * 1024 + lane * 16) = o;
  } else if (bx < 2304) {              // W1 [1024,4096] -> qw1t frags [4096 n, 1024 k]
    int id = (bx - 2048) * 256 + tid;  // 65536 tasks: 4 cols x 16 k each
    int n4 = id & 1023, kc = id >> 10; // col=n4*4, kc in 0..63 (16-k chunks)
    const int col = n4 * 4;
    float4 cm = {0.f, 0.f, 0.f, 0.f};
#pragma unroll
    for (int sp = 0; sp < 16; ++sp) {
      float4 p = *(const float4*)(pcm1 + sp * 4096 + col);
      cm.x = fmaxf(cm.x, p.x); cm.y = fmaxf(cm.y, p.y);
      cm.z = fmaxf(cm.z, p.z); cm.w = fmaxf(cm.w, p.w);
    }
    if (kc == 0) *(float4*)(cm1 + col) = cm;
    const float s0 = 127.0f / fmaxf(cm.x, EPSQ), s1 = 127.0f / fmaxf(cm.y, EPSQ);
    const float s2 = 127.0f / fmaxf(cm.z, EPSQ), s3 = 127.0f / fmaxf(cm.w, EPSQ);
    union { int8_t p[16]; uint4 v; } u0, u1, u2, u3;
#pragma unroll
    for (int j = 0; j < 16; ++j) {
      float4 f = *(const float4*)(W1 + (size_t)(kc * 16 + j) * 4096 + col);
      u0.p[j] = (int8_t)qmb(f.x, s0); u1.p[j] = (int8_t)qmb(f.y, s1);
      u2.p[j] = (int8_t)qmb(f.z, s2); u3.p[j] = (int8_t)qmb(f.w, s3);
    }
    // frag-order dest: frag=((col>>5)*(1024/32) + (kc>>1)), half=(kc&1)
    int8_t* base = qw1 + ((size_t)(col >> 5) * 32 + (kc >> 1)) * 1024 +
                   (kc & 1) * 512 + (col & 31) * 16;
    *(uint4*)(base) = u0.v;      *(uint4*)(base + 16) = u1.v;
    *(uint4*)(base + 32) = u2.v; *(uint4*)(base + 48) = u3.v;
  } else {                             // W2 [4096,1024] -> qw2t frags [1024 n, 4096 k]
    int id = (bx - 2304) * 256 + tid;  // 65536 tasks
    int n4 = id & 255, kc = id >> 8;   // col=n4*4, kc in 0..255
    const int col = n4 * 4;
    float4 cm = {0.f, 0.f, 0.f, 0.f};
#pragma unroll
    for (int sp = 0; sp < 64; ++sp) {
      float4 p = *(const float4*)(pcm2 + sp * 1024 + col);
      cm.x = fmaxf(cm.x, p.x); cm.y = fmaxf(cm.y, p.y);
      cm.z = fmaxf(cm.z, p.z); cm.w = fmaxf(cm.w, p.w);
    }
    if (kc == 0) *(float4*)(cm2 + col) = cm;
    const float s0 = 127.0f / fmaxf(cm.x, EPSQ), s1 = 127.0f / fmaxf(cm.y, EPSQ);
    const float s2 = 127.0f / fmaxf(cm.z, EPSQ), s3 = 127.0f / fmaxf(cm.w, EPSQ);
    union { int8_t p[16]; uint4 v; } u0, u1, u2, u3;
#pragma unroll
    for (int j = 0; j < 16; ++j) {
      float4 f = *(const float4*)(W2 + (size_t)(kc * 16 + j) * 1024 + col);
      u0.p[j] = (int8_t)qmb(f.x, s0); u1.p[j] = (int8_t)qmb(f.y, s1);
      u2.p[j] = (int8_t)qmb(f.z, s2); u3.p[j] = (int8_t)qmb(f.w, s3);
    }
    int8_t* base = qw2 + ((size_t)(col >> 5) * 128 + (kc >> 1)) * 1024 +
                   (kc & 1) * 512 + (col & 31) * 16;
    *(uint4*)(base) = u0.v;      *(uint4*)(base + 16) = u1.v;
    *(uint4*)(base + 32) = u2.v; *(uint4*)(base + 48) = u3.v;
  }
}

// ====== GEMM1: qx [M=8192, K=1024] x qw1t [N=4096, K].
// 8 waves (4m x 2n), 256x128 tile, acc[2][2]/wave, K-step 64, 3-buffer LDS
// (A 16KB + B 8KB per buf), counted-vmcnt(3) pipeline, grid 1024 (2 blk/CU).
// Output: h fp16 in FRAGMENT ORDER (direct stores) + per-block masked hmax. ======
__global__ __launch_bounds__(512, 4) void gemm1(
    const int8_t* __restrict__ A, const int8_t* __restrict__ Bt,
    const float* __restrict__ sxp, const float* __restrict__ cmax,
    const float* __restrict__ bias, const float* __restrict__ mask,
    unsigned short* __restrict__ hfrag, float* __restrict__ pmaxH) {
  constexpr int NST = 16;              // K=1024 / 64
  constexpr int BUF = 24576;           // A 16KB + B 8KB
  __shared__ __align__(16) int8_t smem[3 * BUF];
  const int tid = threadIdx.x;
  const int wave = tid >> 6, lane = tid & 63;

  // XCD swizzle: xcd owns m-tiles [4*xcd, 4*xcd+4) x all 32 n-tiles.
  const int bid = blockIdx.x;
  const int xcd = bid & 7, sl = bid >> 3;            // sl in 0..127
  const int m0 = (xcd * 4 + (sl & 3)) * 256;
  const int n0 = (sl >> 2) * 128;

  v16i acc[2][2] = {};

  // staging per wave: A frags (rb=wave, kc=0/1), B frag (nb=wave&3, kcB=wave>>2)
  const int8_t* gA = A  + ((size_t)((m0 >> 5) + wave) * 32) * 1024 + lane * 16;
  const int8_t* gB = Bt + ((size_t)((n0 >> 5) + (wave & 3)) * 32 + (wave >> 2)) * 1024
                     + lane * 16;
  const int dAo = wave * 1024 + lane * 16;           // kc=0; kc=1 at +8192
  const int dBo = 16384 + ((wave >> 2) * 4 + (wave & 3)) * 1024 + lane * 16;

  // prologue: stage tiles 0 and 1 (3 loads each per wave)
  async16(gA,        smem + dAo);
  async16(gA + 1024, smem + dAo + 8192);
  async16(gB,        smem + dBo);
  async16(gA + 2048, smem + BUF + dAo);
  async16(gA + 3072, smem + BUF + dAo + 8192);
  async16(gB + 2048, smem + BUF + dBo);
  asm volatile("s_waitcnt vmcnt(3)" ::: "memory");   // tile0 landed; tile1 flies
  __builtin_amdgcn_s_barrier();
  __builtin_amdgcn_sched_barrier(0);

  const int mI = (wave & 3) * 2, nI = (wave >> 2) * 2;
#pragma unroll
  for (int kb = 0; kb < NST; ++kb) {
    const int co = (kb % 3) * BUF;
    if (kb + 2 < NST) {                              // issue tile kb+2
      const int po = ((kb + 2) % 3) * BUF;
      async16(gA + (kb + 2) * 2048,        smem + po + dAo);
      async16(gA + (kb + 2) * 2048 + 1024, smem + po + dAo + 8192);
      async16(gB + (kb + 2) * 2048,        smem + po + dBo);
    }
    __builtin_amdgcn_sched_barrier(0);
#pragma unroll
    for (int kc = 0; kc < 2; ++kc) {
      v4i af0 = *(const v4i*)(smem + co + (kc * 8 + mI) * 1024 + lane * 16);
      v4i af1 = *(const v4i*)(smem + co + (kc * 8 + mI + 1) * 1024 + lane * 16);
      v4i bf0 = *(const v4i*)(smem + co + 16384 + (kc * 4 + nI) * 1024 + lane * 16);
      v4i bf1 = *(const v4i*)(smem + co + 16384 + (kc * 4 + nI + 1) * 1024 + lane * 16);
      acc[0][0] = __builtin_amdgcn_mfma_i32_32x32x32_i8(af0, bf0, acc[0][0], 0, 0, 0);
      acc[0][1] = __builtin_amdgcn_mfma_i32_32x32x32_i8(af0, bf1, acc[0][1], 0, 0, 0);
      acc[1][0] = __builtin_amdgcn_mfma_i32_32x32x32_i8(af1, bf0, acc[1][0], 0, 0, 0);
      acc[1][1] = __builtin_amdgcn_mfma_i32_32x32x32_i8(af1, bf1, acc[1][1], 0, 0, 0);
    }
    if (kb + 1 < NST) {
      asm volatile("s_waitcnt lgkmcnt(0)" ::: "memory");   // ds reads done
      if (kb + 2 < NST)
        asm volatile("s_waitcnt vmcnt(3)" ::: "memory");   // kb+1 landed; kb+2 flies
      else
        asm volatile("s_waitcnt vmcnt(0)" ::: "memory");   // tail drain
      __builtin_amdgcn_s_barrier();
      __builtin_amdgcn_sched_barrier(0);
    }
  }

  // epilogue: C/D layout col=lane&31, row=(reg&3)+8*(reg>>2)+4*(lane>>5).
  // h fp16 FRAG ORDER direct stores; masked hmax reduce.
  const float asc = fmaxf(sxp[0], EPSQ) * (1.0f / 127.0f);
  const int cl = lane & 31;
  const int rbase = 4 * (lane >> 5);
  const int wr = wave & 3, wc = wave >> 2;
  float bsc[2], bv[2];
#pragma unroll
  for (int nt = 0; nt < 2; ++nt) {
    const int col = n0 + wc * 64 + nt * 32 + cl;
    bsc[nt] = fmaxf(cmax[col], EPSQ) * (1.0f / 127.0f) * asc;
    bv[nt] = bias[col];
  }
  const int hwoff = (cl >> 4) * 512 + (cl & 15);     // within-frag halfword for k=cl
  float lmax = 0.f;
#pragma unroll
  for (int mt = 0; mt < 2; ++mt) {
    const int rowbase = m0 + wr * 64 + mt * 32;
    const size_t rowblk = (size_t)(rowbase >> 5);
#pragma unroll
    for (int g = 0; g < 4; ++g)
#pragma unroll
      for (int r2 = 0; r2 < 4; ++r2) {
        const int rloc = g * 8 + r2 + rbase;
        const float mk = fabsf(mask[rowbase + rloc]);
#pragma unroll
        for (int nt = 0; nt < 2; ++nt) {
          const size_t kblk = (size_t)((n0 + wc * 64 + nt * 32) >> 5);
          float v = (float)acc[mt][nt][g * 4 + r2] * bsc[nt] + bv[nt];
          v = fmaxf(v, 0.f);
          hfrag[(rowblk * 128 + kblk) * 1024 + hwoff + rloc * 16] = f2h(v);
          lmax = fmaxf(lmax, v * mk);
        }
      }
  }
  for (int s = 32; s; s >>= 1) lmax = fmaxf(lmax, __shfl_down(lmax, s));
  __syncthreads();                     // loop LDS traffic fully done; reuse smem
  float* redf = (float*)smem;
  if (lane == 0) redf[wave] = lmax;
  __syncthreads();
  if (tid == 0) {
    float r = redf[0];
#pragma unroll
    for (int j = 1; j < 8; ++j) r = fmaxf(r, redf[j]);
    pmaxH[bid] = r;
  }
}

// ====== GEMM2 (fused): hfrag fp16 [M=8192, K=4096] x qw2t [N=1024, K].
// 4 waves (2m x 2n), 128x128 tile, acc[2][2]/wave, K-step 64, grid 512 (2 blk/CU).
// PHASE-SPLIT schedule: per K-step two phases {bar -> ds_read one kc ->
// stage-issue -> lgkmcnt(0) -> setprio(1) MFMA x4}. 4-buffer LDS ring (64KB).
// A (fp16) loaded->reg 2 steps ahead, quant+ds_write 2 steps ahead; B async16
// 2 steps ahead. No steady-state vmcnt drain (transitive in-order retirement
// via the compiler's wait on younger A-prefetch regs); tail drains explicitly.
// Out f32 = deq + bias. ======
__global__ __launch_bounds__(256, 2) void gemm2(
    const unsigned short* __restrict__ hfrag, const int8_t* __restrict__ Bt,
    const float* __restrict__ pmaxH, const float* __restrict__ cmax,
    const float* __restrict__ bias, float* __restrict__ out) {
  constexpr int NST = 64;              // K=4096 / 64
  __shared__ __align__(16) int8_t smem[4 * 16384];   // 4 bufs x (A 8K + B 8K)
  const int tid = threadIdx.x;
  const int wave = tid >> 6, lane = tid & 63;

  // hmax = max over 1024 pmaxH partials (red overlaps smem; barrier-fenced)
  float* red = (float*)smem;
  float v = 0.f;
#pragma unroll
  for (int j = 0; j < 4; ++j) v = fmaxf(v, pmaxH[tid + 256 * j]);
  for (int s = 32; s; s >>= 1) v = fmaxf(v, __shfl_down(v, s));
  if (lane == 0) red[wave] = v;
  __syncthreads();
  const float hmax = fmaxf(fmaxf(red[0], red[1]), fmaxf(red[2], red[3]));
  __syncthreads();                     // red consumed before staging overwrites
  const float asc = fmaxf(hmax, EPSQ) * (1.0f / 127.0f);
  const __half sh = __float2half_rn(127.0f / fmaxf(hmax, EPSQ));
  const __half2 s2 = __halves2half2(sh, sh);
  const __half mh = __float2half_rn(1536.0f);
  const __half2 m2 = __halves2half2(mh, mh);

  // XCD swizzle: xcd owns 8 contiguous m-tiles x all 8 n-tiles.
  const int bid = blockIdx.x;
  const int xcd = bid & 7, slot = bid >> 3;
  const int m0 = ((xcd << 3) + (slot >> 3)) * 128;
  const int n0 = (slot & 7) * 128;

  v16i acc[2][2] = {};

  // staging per wave: A frags (rb=wave, kc=0/1) from fp16 hfrag via regs;
  // B frags (nb=wave, kc=0/1) via async16.  Kf = 4096/32 = 128.
  const uint4* hA = (const uint4*)hfrag;          // frag = 128 uint4
  const size_t aBase = ((size_t)((m0 >> 5) + wave) * 128) * 128 + lane * 2;
  const int8_t* gB = Bt + ((size_t)((n0 >> 5) + wave) * 128) * 1024 + lane * 16;
  // buf-relative LDS byte offsets
  const int dA0o = (0 * 4 + wave) * 1024 + lane * 16;
  const int dA1o = (1 * 4 + wave) * 1024 + lane * 16;
  const int dB0o = 8192 + (0 * 4 + wave) * 1024 + lane * 16;
  const int dB1o = 8192 + (1 * 4 + wave) * 1024 + lane * 16;
  const int mI = (wave & 1) * 2, nI = (wave >> 1) * 2;

  uint4 ra0, ra1, rc0, rc1;            // A-fp16 prefetch (single set, 2 ahead)

  // ---- prologue: A(0),A(1) quant->buf0/1; B(0),B(1) DMA; A(2)->regs ----
  {
    uint4 a0 = hA[aBase], a1 = hA[aBase + 1];            // A(0) kc0
    uint4 c0 = hA[aBase + 128], c1 = hA[aBase + 129];    // A(0) kc1
    __builtin_amdgcn_sched_barrier(0);                   // A(0) issued first
    async16(gB,            smem + dB0o);                 // B(0)
    async16(gB + 1024,     smem + dB1o);
    async16(gB + 2 * 1024, smem + 16384 + dB0o);         // B(1)
    async16(gB + 3 * 1024, smem + 16384 + dB1o);
    __builtin_amdgcn_sched_barrier(0);                   // B before A(1) loads
    uint4 o;
    o.x = q4h(a0.x, a0.y, s2, m2); o.y = q4h(a0.z, a0.w, s2, m2);
    o.z = q4h(a1.x, a1.y, s2, m2); o.w = q4h(a1.z, a1.w, s2, m2);
    *(uint4*)(smem + dA0o) = o;
    o.x = q4h(c0.x, c0.y, s2, m2); o.y = q4h(c0.z, c0.w, s2, m2);
    o.z = q4h(c1.x, c1.y, s2, m2); o.w = q4h(c1.z, c1.w, s2, m2);
    *(uint4*)(smem + dA1o) = o;
    __builtin_amdgcn_sched_barrier(0);
    a0 = hA[aBase + 2 * 128]; a1 = hA[aBase + 2 * 128 + 1];   // A(1)
    c0 = hA[aBase + 3 * 128]; c1 = hA[aBase + 3 * 128 + 1];
    __builtin_amdgcn_sched_barrier(0);
    o.x = q4h(a0.x, a0.y, s2, m2); o.y = q4h(a0.z, a0.w, s2, m2);
    o.z = q4h(a1.x, a1.y, s2, m2); o.w = q4h(a1.z, a1.w, s2, m2);
    *(uint4*)(smem + 16384 + dA0o) = o;                  // waits A(1) -> B(0),B(1) landed
    o.x = q4h(c0.x, c0.y, s2, m2); o.y = q4h(c0.z, c0.w, s2, m2);
    o.z = q4h(c1.x, c1.y, s2, m2); o.w = q4h(c1.z, c1.w, s2, m2);
    *(uint4*)(smem + 16384 + dA1o) = o;
    __builtin_amdgcn_sched_barrier(0);
    ra0 = hA[aBase + 4 * 128]; ra1 = hA[aBase + 4 * 128 + 1]; // A(2) -> regs
    rc0 = hA[aBase + 5 * 128]; rc1 = hA[aBase + 5 * 128 + 1];
  }
  asm volatile("s_waitcnt lgkmcnt(0)" ::: "memory");     // A-writes visible
  __builtin_amdgcn_sched_barrier(0);

#pragma unroll 4
  for (int kb = 0; kb < NST; ++kb) {
    const int cb = (kb & 3) * 16384;
    const int nb2 = ((kb + 2) & 3) * 16384;
    // ---------------- phase 0 (kc = 0) ----------------
    __builtin_amdgcn_s_barrier();
    __builtin_amdgcn_sched_barrier(0);
    {
      v4i af0 = *(const v4i*)(smem + cb + (0 * 4 + mI) * 1024 + lane * 16);
      v4i af1 = *(const v4i*)(smem + cb + (0 * 4 + mI + 1) * 1024 + lane * 16);
      v4i bf0 = *(const v4i*)(smem + cb + 8192 + (0 * 4 + nI) * 1024 + lane * 16);
      v4i bf1 = *(const v4i*)(smem + cb + 8192 + (0 * 4 + nI + 1) * 1024 + lane * 16);
      if (kb + 2 < NST) {                                // B(kb+2) DMA
        async16(gB + (size_t)((kb + 2) * 2) * 1024,     smem + nb2 + dB0o);
        async16(gB + (size_t)((kb + 2) * 2 + 1) * 1024, smem + nb2 + dB1o);
      }
      asm volatile("s_waitcnt lgkmcnt(0)" ::: "memory");
      __builtin_amdgcn_sched_barrier(0);
      __builtin_amdgcn_s_setprio(1);
      acc[0][0] = __builtin_amdgcn_mfma_i32_32x32x32_i8(af0, bf0, acc[0][0], 0, 0, 0);
      acc[0][1] = __builtin_amdgcn_mfma_i32_32x32x32_i8(af0, bf1, acc[0][1], 0, 0, 0);
      acc[1][0] = __builtin_amdgcn_mfma_i32_32x32x32_i8(af1, bf0, acc[1][0], 0, 0, 0);
      acc[1][1] = __builtin_amdgcn_mfma_i32_32x32x32_i8(af1, bf1, acc[1][1], 0, 0, 0);
      __builtin_amdgcn_s_setprio(0);
      __builtin_amdgcn_sched_barrier(0);
    }
    // ---------------- phase 1 (kc = 1) ----------------
    __builtin_amdgcn_s_barrier();
    __builtin_amdgcn_sched_barrier(0);
    {
      v4i af0 = *(const v4i*)(smem + cb + (1 * 4 + mI) * 1024 + lane * 16);
      v4i af1 = *(const v4i*)(smem + cb + (1 * 4 + mI + 1) * 1024 + lane * 16);
      v4i bf0 = *(const v4i*)(smem + cb + 8192 + (1 * 4 + nI) * 1024 + lane * 16);
      v4i bf1 = *(const v4i*)(smem + cb + 8192 + (1 * 4 + nI + 1) * 1024 + lane * 16);
      if (kb + 2 < NST) {
        // quant A(kb+2) from regs loaded one step ago -> buf ring +2
        uint4 o;
        o.x = q4h(ra0.x, ra0.y, s2, m2); o.y = q4h(ra0.z, ra0.w, s2, m2);
        o.z = q4h(ra1.x, ra1.y, s2, m2); o.w = q4h(ra1.z, ra1.w, s2, m2);
        *(uint4*)(smem + nb2 + dA0o) = o;
        o.x = q4h(rc0.x, rc0.y, s2, m2); o.y = q4h(rc0.z, rc0.w, s2, m2);
        o.z = q4h(rc1.x, rc1.y, s2, m2); o.w = q4h(rc1.z, rc1.w, s2, m2);
        *(uint4*)(smem + nb2 + dA1o) = o;
        __builtin_amdgcn_sched_barrier(0);
        if (kb + 3 < NST) {                              // A(kb+3) -> regs
          const size_t ai = aBase + (size_t)((kb + 3) * 2) * 128;
          ra0 = hA[ai]; ra1 = hA[ai + 1];
          rc0 = hA[ai + 128]; rc1 = hA[ai + 129];
        }
      } else {
        asm volatile("s_waitcnt vmcnt(0)" ::: "memory"); // tail: drain B(NST-1)
      }
      asm volatile("s_waitcnt lgkmcnt(0)" ::: "memory"); // reads + A-writes done
      __builtin_amdgcn_sched_barrier(0);
      __builtin_amdgcn_s_setprio(1);
      acc[0][0] = __builtin_amdgcn_mfma_i32_32x32x32_i8(af0, bf0, acc[0][0], 0, 0, 0);
      acc[0][1] = __builtin_amdgcn_mfma_i32_32x32x32_i8(af0, bf1, acc[0][1], 0, 0, 0);
      acc[1][0] = __builtin_amdgcn_mfma_i32_32x32x32_i8(af1, bf0, acc[1][0], 0, 0, 0);
      acc[1][1] = __builtin_amdgcn_mfma_i32_32x32x32_i8(af1, bf1, acc[1][1], 0, 0, 0);
      __builtin_amdgcn_s_setprio(0);
      __builtin_amdgcn_sched_barrier(0);
    }
  }

  // epilogue: out f32 row-major [8192,1024]; wave owns 64x64
  const int cl = lane & 31;
  const int rbase = 4 * (lane >> 5);
  const int wr = wave & 1, wc = wave >> 1;
  float bsc[2], bv[2];
  int colv[2];
#pragma unroll
  for (int nt = 0; nt < 2; ++nt) {
    colv[nt] = n0 + wc * 64 + nt * 32 + cl;
    bsc[nt] = fmaxf(cmax[colv[nt]], EPSQ) * (1.0f / 127.0f) * asc;
    bv[nt] = bias[colv[nt]];
  }
#pragma unroll
  for (int mt = 0; mt < 2; ++mt)
#pragma unroll
    for (int g = 0; g < 4; ++g)
#pragma unroll
      for (int r2 = 0; r2 < 4; ++r2) {
        const int row = m0 + wr * 64 + mt * 32 + g * 8 + r2 + rbase;
#pragma unroll
        for (int nt = 0; nt < 2; ++nt)
          out[(size_t)row * 1024 + colv[nt]] =
              (float)acc[mt][nt][g * 4 + r2] * bsc[nt] + bv[nt];
      }
}

extern "C" void kernel_launch(void* const* d_in, const int* in_sizes, int n_in,
                              void* d_out, int out_size, void* d_ws, size_t ws_size,
                              hipStream_t stream) {
  const float* x  = (const float*)d_in[0];   // [8192,1024]
  const float* mk = (const float*)d_in[1];   // [8192]
  const float* W1 = (const float*)d_in[2];   // [1024,4096]
  const float* b1 = (const float*)d_in[3];   // [4096]
  const float* W2 = (const float*)d_in[4];   // [4096,1024]
  const float* b2 = (const float*)d_in[5];   // [1024]
  float* out = (float*)d_out;                // [8192,1024]

  float* scG   = (float*)d_ws;               // [8]
  float* pmaxX = scG + 8;                    // [1024]
  float* pmaxH = pmaxX + 1024;               // [2048] (1024 used)
  float* pcm1  = pmaxH + 2048;               // [16*4096]
  float* pcm2  = pcm1 + 65536;               // [64*1024]
  float* cm1   = pcm2 + 65536;               // [4096]
  float* cm2   = cm1 + 4096;                 // [1024]
  int8_t* qx  = (int8_t*)(cm2 + 1024);           // 8 MiB  frag order
  int8_t* qw1 = qx  + (size_t)8192 * 1024;       // 4 MiB  frag order [4096 n][1024 k]
  int8_t* qw2 = qw1 + (size_t)4096 * 1024;       // 4 MiB  frag order [1024 n][4096 k]
  unsigned short* h = (unsigned short*)(qw2 + (size_t)1024 * 4096);  // 64 MiB fp16 frag order

  k_stats<<<1152, 256, 0, stream>>>(x, mk, W1, W2, pmaxX, pcm1, pcm2);
  k_quant<<<2560, 256, 0, stream>>>(x, W1, W2, pmaxX, pcm1, pcm2,
                                    qx, qw1, qw2, cm1, cm2, scG);
  gemm1<<<1024, 512, 0, stream>>>(qx, qw1, scG, cm1, b1, mk, h, pmaxH);
  gemm2<<<512, 256, 0, stream>>>(h, qw2, pmaxH, cm2, b2, out);
}

// Round 6
// 225.373 us; speedup vs baseline: 1.0201x; 1.0201x over previous
//
#include <hip/hip_runtime.h>
#include <hip/hip_fp16.h>
#include <stdint.h>

// AQT int8 MLP: M=8192, C=1024, H=4096. All I/O float32.
// Exact path: fake_quant values are q/s (integer q), so xq@wq is exact in int32 MFMA.
// 4 dispatches: stats -> quant(x,W1t,W2t) -> GEMM1(h fp16-frag + block hmax)
//            -> GEMM2 (fused: hmax reduce + packed magic-quant of h + GEMM + bias).
//
// int8 operands in MFMA-FRAGMENT ORDER: frag = 1KB = 32 rows x 32 k;
//   byte lane*16+j <-> (row=lane&31, k=(lane>>5)*16+j); frag id = rowblk*(K/32)+kblk.
// h stored fp16 in fragment order: frag = 2KB; halfword ((k>>4)*32+r)*16+(k&15).
// Magic quant: fp32 fma(x,s,1.5*2^23) -> low byte = int8 q; fp16 hfma2(h,s,1536).
//
// Round-5 postmortem: LDS port is the structural roofline (operand KB/MFMA vs
// 85 B/cy) -> cap ~44% MfmaUtil for LDS-fed designs. Fix: A operands now load
// GLOBAL->REGISTER (frag layout == load layout, 16B/lane); only B uses a 2-slot
// LDS ring. Cross-wave DMA visibility via {own vmcnt(4) -> s_barrier} per step.
// GEMM1: 8 waves 4mx2n, 256x128, acc[2][2], A=qx direct (2x dup absorbed by L1).
// GEMM2: 4 waves, 128x128, wave=32m x 128n EXCLUSIVE, acc[4], A=hfrag fp16 ->
//   reg quant (no LDS-A, no duplication of fp16 L2 traffic).

#define EPSQ 1e-6f
typedef int v4i __attribute__((ext_vector_type(4)));
typedef int v16i __attribute__((ext_vector_type(16)));

__device__ __forceinline__ void async16(const int8_t* g, int8_t* l) {
  __builtin_amdgcn_global_load_lds(
      (const __attribute__((address_space(1))) void*)g,
      (__attribute__((address_space(3))) void*)l, 16, 0, 0);
}
__device__ __forceinline__ unsigned short f2h(float f) {
  __half h = __float2half(f);
  return *(unsigned short*)&h;
}
__device__ __forceinline__ float4 max4(float4 m, float4 v) {
  m.x = fmaxf(m.x, fabsf(v.x)); m.y = fmaxf(m.y, fabsf(v.y));
  m.z = fmaxf(m.z, fabsf(v.z)); m.w = fmaxf(m.w, fabsf(v.w));
  return m;
}
// fp32 magic quant: |x*s| <= 127 guaranteed by construction (s = 127/absmax).
__device__ __forceinline__ unsigned qmb(float x, float s) {
  return __float_as_uint(fmaf(x, s, 12582912.0f)) & 0xffu;   // 1.5*2^23
}
__device__ __forceinline__ unsigned q4f(float4 f, float s) {
  return qmb(f.x, s) | (qmb(f.y, s) << 8) | (qmb(f.z, s) << 16) |
         (__float_as_uint(fmaf(f.w, s, 12582912.0f)) << 24);
}
// fp16 packed magic quant: two halfs -> ... -> select low bytes of 4 halfs.
__device__ __forceinline__ unsigned q4h(unsigned ua, unsigned ub,
                                        __half2 s2, __half2 m2) {
  __half2 ha = __hfma2(*(__half2*)&ua, s2, m2);
  __half2 hb = __hfma2(*(__half2*)&ub, s2, m2);
  unsigned va = *(unsigned*)&ha, vb = *(unsigned*)&hb;
#if __has_builtin(__builtin_amdgcn_perm)
  return __builtin_amdgcn_perm(vb, va, 0x06040200u);
#else
  return (va & 0xffu) | ((va >> 8) & 0xff00u) |
         ((vb & 0xffu) << 16) | (((vb >> 8) & 0xff00u) << 16);
#endif
}

// ===== dispatch 1: stats. W1: 16 rowsplits x 4 colgroups; W2: 64 rowsplits;
// x masked absmax: 1024 blk. =====
__global__ __launch_bounds__(256) void k_stats(
    const float* __restrict__ x, const float* __restrict__ mask,
    const float* __restrict__ W1, const float* __restrict__ W2,
    float* __restrict__ pmaxX, float* __restrict__ pcm1, float* __restrict__ pcm2) {
  const int bx = blockIdx.x, tid = threadIdx.x;
  if (bx < 64) {                       // W1 [1024,4096]
    const int sp = bx & 15, cg = bx >> 4;
    const int col = cg * 1024 + tid * 4;
    float4 m = {0.f, 0.f, 0.f, 0.f};
#pragma unroll 8
    for (int r = 0; r < 64; ++r)
      m = max4(m, *(const float4*)(W1 + (size_t)(sp * 64 + r) * 4096 + col));
    *(float4*)(pcm1 + sp * 4096 + col) = m;
  } else if (bx < 128) {               // W2 [4096,1024]
    const int sp = bx - 64;
    const int col = tid * 4;
    float4 m = {0.f, 0.f, 0.f, 0.f};
#pragma unroll 8
    for (int r = 0; r < 64; ++r)
      m = max4(m, *(const float4*)(W2 + (size_t)(sp * 64 + r) * 1024 + col));
    *(float4*)(pcm2 + sp * 1024 + col) = m;
  } else {                             // masked absmax of x -> per-block partial
    __shared__ float red[4];
    const int b = bx - 128;            // 1024 blocks
    float lmax = 0.f;
    for (int c = b * 256 + tid; c < 1048576; c += 262144) {
      size_t idx = (size_t)c * 8;
      float mk = fabsf(mask[idx >> 10]);
      float4 m4 = {0.f, 0.f, 0.f, 0.f};
      m4 = max4(m4, *(const float4*)(x + idx));
      m4 = max4(m4, *(const float4*)(x + idx + 4));
      lmax = fmaxf(lmax, fmaxf(fmaxf(m4.x, m4.y), fmaxf(m4.z, m4.w)) * mk);
    }
    for (int s = 32; s; s >>= 1) lmax = fmaxf(lmax, __shfl_down(lmax, s));
    if ((tid & 63) == 0) red[tid >> 6] = lmax;
    __syncthreads();
    if (tid == 0)
      pmaxX[b] = fmaxf(fmaxf(red[0], red[1]), fmaxf(red[2], red[3]));
  }
}

// ===== dispatch 2: quantize x (2048 blk, frag order), W1->qW1t (256), W2->qW2t (256)
__global__ __launch_bounds__(256) void k_quant(
    const float* __restrict__ x, const float* __restrict__ W1, const float* __restrict__ W2,
    const float* __restrict__ pmaxX, const float* __restrict__ pcm1, const float* __restrict__ pcm2,
    int8_t* __restrict__ qx, int8_t* __restrict__ qw1, int8_t* __restrict__ qw2,
    float* __restrict__ cm1, float* __restrict__ cm2, float* __restrict__ scG) {
  const int bx = blockIdx.x, tid = threadIdx.x;
  if (bx < 2048) {                     // x [8192,1024] -> qx frag order
    __shared__ float red[4];
    float v = fmaxf(fmaxf(pmaxX[tid], pmaxX[tid + 256]),
                    fmaxf(pmaxX[tid + 512], pmaxX[tid + 768]));
    for (int s = 32; s; s >>= 1) v = fmaxf(v, __shfl_down(v, s));
    if ((tid & 63) == 0) red[tid >> 6] = v;
    __syncthreads();
    const float xmax = fmaxf(fmaxf(red[0], red[1]), fmaxf(red[2], red[3]));
    if (bx == 0 && tid == 0) scG[0] = xmax;
    const float s = 127.0f / fmaxf(xmax, EPSQ);
    const int wave = tid >> 6, lane = tid & 63;
    const int f = bx * 4 + wave;                   // frag id; Kf = 1024/32 = 32
    const int r = (f >> 5) * 32 + (lane & 31);
    const int k = (f & 31) * 32 + (lane >> 5) * 16;
    const float4* src = (const float4*)(x + (size_t)r * 1024 + k);
    uint4 o;
    o.x = q4f(src[0], s); o.y = q4f(src[1], s);
    o.z = q4f(src[2], s); o.w = q4f(src[3], s);
    *(uint4*)(qx + (size_t)f * 1024 + lane * 16) = o;
  } else if (bx < 2304) {              // W1 [1024,4096] -> qw1t frags [4096 n, 1024 k]
    int id = (bx - 2048) * 256 + tid;  // 65536 tasks: 4 cols x 16 k each
    int n4 = id & 1023, kc = id >> 10; // col=n4*4, kc in 0..63 (16-k chunks)
    const int col = n4 * 4;
    float4 cm = {0.f, 0.f, 0.f, 0.f};
#pragma unroll
    for (int sp = 0; sp < 16; ++sp) {
      float4 p = *(const float4*)(pcm1 + sp * 4096 + col);
      cm.x = fmaxf(cm.x, p.x); cm.y = fmaxf(cm.y, p.y);
      cm.z = fmaxf(cm.z, p.z); cm.w = fmaxf(cm.w, p.w);
    }
    if (kc == 0) *(float4*)(cm1 + col) = cm;
    const float s0 = 127.0f / fmaxf(cm.x, EPSQ), s1 = 127.0f / fmaxf(cm.y, EPSQ);
    const float s2 = 127.0f / fmaxf(cm.z, EPSQ), s3 = 127.0f / fmaxf(cm.w, EPSQ);
    union { int8_t p[16]; uint4 v; } u0, u1, u2, u3;
#pragma unroll
    for (int j = 0; j < 16; ++j) {
      float4 f = *(const float4*)(W1 + (size_t)(kc * 16 + j) * 4096 + col);
      u0.p[j] = (int8_t)qmb(f.x, s0); u1.p[j] = (int8_t)qmb(f.y, s1);
      u2.p[j] = (int8_t)qmb(f.z, s2); u3.p[j] = (int8_t)qmb(f.w, s3);
    }
    // frag-order dest: frag=((col>>5)*(1024/32) + (kc>>1)), half=(kc&1)
    int8_t* base = qw1 + ((size_t)(col >> 5) * 32 + (kc >> 1)) * 1024 +
                   (kc & 1) * 512 + (col & 31) * 16;
    *(uint4*)(base) = u0.v;      *(uint4*)(base + 16) = u1.v;
    *(uint4*)(base + 32) = u2.v; *(uint4*)(base + 48) = u3.v;
  } else {                             // W2 [4096,1024] -> qw2t frags [1024 n, 4096 k]
    int id = (bx - 2304) * 256 + tid;  // 65536 tasks
    int n4 = id & 255, kc = id >> 8;   // col=n4*4, kc in 0..255
    const int col = n4 * 4;
    float4 cm = {0.f, 0.f, 0.f, 0.f};
#pragma unroll
    for (int sp = 0; sp < 64; ++sp) {
      float4 p = *(const float4*)(pcm2 + sp * 1024 + col);
      cm.x = fmaxf(cm.x, p.x); cm.y = fmaxf(cm.y, p.y);
      cm.z = fmaxf(cm.z, p.z); cm.w = fmaxf(cm.w, p.w);
    }
    if (kc == 0) *(float4*)(cm2 + col) = cm;
    const float s0 = 127.0f / fmaxf(cm.x, EPSQ), s1 = 127.0f / fmaxf(cm.y, EPSQ);
    const float s2 = 127.0f / fmaxf(cm.z, EPSQ), s3 = 127.0f / fmaxf(cm.w, EPSQ);
    union { int8_t p[16]; uint4 v; } u0, u1, u2, u3;
#pragma unroll
    for (int j = 0; j < 16; ++j) {
      float4 f = *(const float4*)(W2 + (size_t)(kc * 16 + j) * 1024 + col);
      u0.p[j] = (int8_t)qmb(f.x, s0); u1.p[j] = (int8_t)qmb(f.y, s1);
      u2.p[j] = (int8_t)qmb(f.z, s2); u3.p[j] = (int8_t)qmb(f.w, s3);
    }
    int8_t* base = qw2 + ((size_t)(col >> 5) * 128 + (kc >> 1)) * 1024 +
                   (kc & 1) * 512 + (col & 31) * 16;
    *(uint4*)(base) = u0.v;      *(uint4*)(base + 16) = u1.v;
    *(uint4*)(base + 32) = u2.v; *(uint4*)(base + 48) = u3.v;
  }
}

// ====== GEMM1: qx [M=8192, K=1024] x qw1t [N=4096, K].
// 8 waves (4m x 2n), 256x128 tile, wave=64x64, acc[2][2].
// A: DIRECT global->reg (parity-double-buffered, 4 x dwordx4/step).
// B: 2-slot LDS ring (16KB), 1 async16/wave/step, {vmcnt(4); s_barrier} per step.
// Output: h fp16 FRAG ORDER direct stores + per-block masked hmax. ======
__global__ __launch_bounds__(512, 4) void gemm1(
    const int8_t* __restrict__ A, const int8_t* __restrict__ Bt,
    const float* __restrict__ sxp, const float* __restrict__ cmax,
    const float* __restrict__ bias, const float* __restrict__ mask,
    unsigned short* __restrict__ hfrag, float* __restrict__ pmaxH) {
  constexpr int NST = 16;              // K=1024 / 64
  __shared__ __align__(16) int8_t smem[2 * 8192];    // B ring only
  const int tid = threadIdx.x;
  const int wave = tid >> 6, lane = tid & 63;

  // XCD swizzle: xcd owns m-tiles [4*xcd, 4*xcd+4) x all 32 n-tiles.
  const int bid = blockIdx.x;
  const int xcd = bid & 7, sl = bid >> 3;            // sl in 0..127
  const int m0 = (xcd * 4 + (sl & 3)) * 256;
  const int n0 = (sl >> 2) * 128;
  const int wr = wave & 3, wc = wave >> 2;           // 4m x 2n wave grid

  v16i acc[2][2] = {};

  // A direct-global: wave reads rowblocks (m0>>5)+wr*2+{0,1}; frag byte =
  // (rb*32 + kb*2 + kc)*1024 + lane*16 ; mt stride 32768, kc stride 1024.
  const int8_t* gA = A + ((size_t)((m0 >> 5) + wr * 2) * 32) * 1024 + lane * 16;
  // B staging: wave stages frag f=wave (kcS=wave>>2, nbS=wave&3).
  const int kcS = wave >> 2, nbS = wave & 3;
  const int8_t* gB = Bt + ((size_t)((n0 >> 5) + nbS) * 32 + kcS) * 1024 + lane * 16;
  const int dBo = wave * 1024 + lane * 16;           // == (kcS*4+nbS)*1024 + ...
  const int rdo = wc * 2048 + lane * 16;             // bf base: (kc*4+wc*2+nt)*1024

  // A parity regs [mt*2+kc]
  v4i aP0, aP1, aP2, aP3, aQ0, aQ1, aQ2, aQ3;

  // prologue: B(0) DMA first (so vmcnt(4) retires it), then A(0)x4 loads.
  async16(gB, smem + dBo);
  __builtin_amdgcn_sched_barrier(0);
  aP0 = *(const v4i*)(gA);
  aP1 = *(const v4i*)(gA + 1024);
  aP2 = *(const v4i*)(gA + 32768);
  aP3 = *(const v4i*)(gA + 32768 + 1024);
  asm volatile("s_waitcnt vmcnt(4)" ::: "memory");   // own B(0) landed; A(0) fly
  __builtin_amdgcn_s_barrier();                      // => ALL waves' B(0) landed
  __builtin_amdgcn_sched_barrier(0);

#pragma unroll 2
  for (int kb = 0; kb < NST; ++kb) {
    const int slot = (kb & 1) * 8192, nslot = slot ^ 8192;
    const bool more = (kb + 1 < NST);
    if (more) {
      async16(gB + (size_t)(kb + 1) * 2048, smem + nslot + dBo);  // B(kb+1)
      __builtin_amdgcn_sched_barrier(0);             // B before A loads (vmcnt order)
      const int8_t* ga = gA + (size_t)(kb + 1) * 2048;
      if (kb & 1) {
        aP0 = *(const v4i*)(ga);         aP1 = *(const v4i*)(ga + 1024);
        aP2 = *(const v4i*)(ga + 32768); aP3 = *(const v4i*)(ga + 32768 + 1024);
      } else {
        aQ0 = *(const v4i*)(ga);         aQ1 = *(const v4i*)(ga + 1024);
        aQ2 = *(const v4i*)(ga + 32768); aQ3 = *(const v4i*)(ga + 32768 + 1024);
      }
      __builtin_amdgcn_sched_barrier(0);
    }
    // compute on A(kb) parity regs + B slot[kb&1]
    {
      const v4i a00 = (kb & 1) ? aQ0 : aP0;   // (mt0,kc0)
      const v4i a01 = (kb & 1) ? aQ1 : aP1;   // (mt0,kc1)
      const v4i a10 = (kb & 1) ? aQ2 : aP2;   // (mt1,kc0)
      const v4i a11 = (kb & 1) ? aQ3 : aP3;   // (mt1,kc1)
      v4i b0 = *(const v4i*)(smem + slot + rdo);
      v4i b1 = *(const v4i*)(smem + slot + rdo + 1024);
      __builtin_amdgcn_s_setprio(1);
      acc[0][0] = __builtin_amdgcn_mfma_i32_32x32x32_i8(a00, b0, acc[0][0], 0, 0, 0);
      acc[0][1] = __builtin_amdgcn_mfma_i32_32x32x32_i8(a00, b1, acc[0][1], 0, 0, 0);
      acc[1][0] = __builtin_amdgcn_mfma_i32_32x32x32_i8(a10, b0, acc[1][0], 0, 0, 0);
      acc[1][1] = __builtin_amdgcn_mfma_i32_32x32x32_i8(a10, b1, acc[1][1], 0, 0, 0);
      __builtin_amdgcn_s_setprio(0);
      v4i b2 = *(const v4i*)(smem + slot + 4096 + rdo);
      v4i b3 = *(const v4i*)(smem + slot + 4096 + rdo + 1024);
      __builtin_amdgcn_s_setprio(1);
      acc[0][0] = __builtin_amdgcn_mfma_i32_32x32x32_i8(a01, b2, acc[0][0], 0, 0, 0);
      acc[0][1] = __builtin_amdgcn_mfma_i32_32x32x32_i8(a01, b3, acc[0][1], 0, 0, 0);
      acc[1][0] = __builtin_amdgcn_mfma_i32_32x32x32_i8(a11, b2, acc[1][0], 0, 0, 0);
      acc[1][1] = __builtin_amdgcn_mfma_i32_32x32x32_i8(a11, b3, acc[1][1], 0, 0, 0);
      __builtin_amdgcn_s_setprio(0);
    }
    if (more) {
      // own B(kb+1) landed (leave A(kb+1)x4 flying), then cross-wave fence.
      asm volatile("s_waitcnt vmcnt(4)" ::: "memory");
      __builtin_amdgcn_s_barrier();
      __builtin_amdgcn_sched_barrier(0);
    }
  }

  // epilogue: C/D layout col=lane&31, row=(reg&3)+8*(reg>>2)+4*(lane>>5).
  // h fp16 FRAG ORDER direct stores; masked hmax reduce.
  const float asc = fmaxf(sxp[0], EPSQ) * (1.0f / 127.0f);
  const int cl = lane & 31;
  const int rbase = 4 * (lane >> 5);
  float bsc[2], bv[2];
#pragma unroll
  for (int nt = 0; nt < 2; ++nt) {
    const int col = n0 + wc * 64 + nt * 32 + cl;
    bsc[nt] = fmaxf(cmax[col], EPSQ) * (1.0f / 127.0f) * asc;
    bv[nt] = bias[col];
  }
  const int hwoff = (cl >> 4) * 512 + (cl & 15);     // within-frag halfword for k=cl
  float lmax = 0.f;
#pragma unroll
  for (int mt = 0; mt < 2; ++mt) {
    const int rowbase = m0 + wr * 64 + mt * 32;
    const size_t rowblk = (size_t)(rowbase >> 5);
#pragma unroll
    for (int g = 0; g < 4; ++g)
#pragma unroll
      for (int r2 = 0; r2 < 4; ++r2) {
        const int rloc = g * 8 + r2 + rbase;
        const float mk = fabsf(mask[rowbase + rloc]);
#pragma unroll
        for (int nt = 0; nt < 2; ++nt) {
          const size_t kblk = (size_t)((n0 + wc * 64 + nt * 32) >> 5);
          float v = (float)acc[mt][nt][g * 4 + r2] * bsc[nt] + bv[nt];
          v = fmaxf(v, 0.f);
          hfrag[(rowblk * 128 + kblk) * 1024 + hwoff + rloc * 16] = f2h(v);
          lmax = fmaxf(lmax, v * mk);
        }
      }
  }
  for (int s = 32; s; s >>= 1) lmax = fmaxf(lmax, __shfl_down(lmax, s));
  __syncthreads();                     // loop LDS traffic fully done; reuse smem
  float* redf = (float*)smem;
  if (lane == 0) redf[wave] = lmax;
  __syncthreads();
  if (tid == 0) {
    float r = redf[0];
#pragma unroll
    for (int j = 1; j < 8; ++j) r = fmaxf(r, redf[j]);
    pmaxH[bid] = r;
  }
}

// ====== GEMM2 (fused): hfrag fp16 [M=8192, K=4096] x qw2t [N=1024, K].
// 4 waves, 128x128 tile, wave = 32m (EXCLUSIVE) x 128n, acc[4].
// A: hfrag fp16 global->reg (parity dbuf) -> q4h quant -> MFMA operand (no LDS).
// B: 2-slot LDS ring, 2 async16/wave/step, {vmcnt(4); s_barrier} per step.
// Out f32 = deq + bias. ======
__global__ __launch_bounds__(256, 3) void gemm2(
    const unsigned short* __restrict__ hfrag, const int8_t* __restrict__ Bt,
    const float* __restrict__ pmaxH, const float* __restrict__ cmax,
    const float* __restrict__ bias, float* __restrict__ out) {
  constexpr int NST = 64;              // K=4096 / 64
  __shared__ __align__(16) int8_t smem[2 * 8192];    // B ring only
  const int tid = threadIdx.x;
  const int wave = tid >> 6, lane = tid & 63;

  // hmax = max over 1024 pmaxH partials (red overlaps smem; barrier-fenced)
  float* red = (float*)smem;
  float v = 0.f;
#pragma unroll
  for (int j = 0; j < 4; ++j) v = fmaxf(v, pmaxH[tid + 256 * j]);
  for (int s = 32; s; s >>= 1) v = fmaxf(v, __shfl_down(v, s));
  if (lane == 0) red[wave] = v;
  __syncthreads();
  const float hmax = fmaxf(fmaxf(red[0], red[1]), fmaxf(red[2], red[3]));
  __syncthreads();                     // red consumed before staging overwrites
  const float asc = fmaxf(hmax, EPSQ) * (1.0f / 127.0f);
  const __half sh = __float2half_rn(127.0f / fmaxf(hmax, EPSQ));
  const __half2 s2 = __halves2half2(sh, sh);
  const __half mh = __float2half_rn(1536.0f);
  const __half2 m2 = __halves2half2(mh, mh);

  // XCD swizzle: xcd owns 8 contiguous m-tiles x all 8 n-tiles.
  const int bid = blockIdx.x;
  const int xcd = bid & 7, slot2 = bid >> 3;
  const int m0 = ((xcd << 3) + (slot2 >> 3)) * 128;
  const int n0 = (slot2 & 7) * 128;

  v16i acc[4] = {};                    // wave owns 32m x 128n (4 n-frags)

  // A: wave's exclusive rowblock rb = (m0>>5)+wave. fp16 frag = 2 uint4/lane.
  // uint4 idx = (rb*128 + kb*2 + kc)*128 + lane*2 (+1 for second half).
  const uint4* hA = (const uint4*)hfrag;
  const size_t aBase = ((size_t)((m0 >> 5) + wave) * 128) * 128 + (size_t)lane * 2;
  // B staging: wave stages frags (kc=0,nb=wave) and (kc=1,nb=wave).
  const int8_t* gB = Bt + ((size_t)((n0 >> 5) + wave) * 128) * 1024 + lane * 16;
  const int dB0o = wave * 1024 + lane * 16;          // kc0 frag slot pos
  const int dB1o = (4 + wave) * 1024 + lane * 16;    // kc1
  const int rdo = lane * 16;

  // A fp16 parity prefetch [kc*2+half]
  uint4 hP0, hP1, hP2, hP3, hQ0, hQ1, hQ2, hQ3;

  // prologue: B(0)x2 DMA first, then A(0)x4 loads.
  async16(gB, smem + dB0o);
  async16(gB + 1024, smem + dB1o);
  __builtin_amdgcn_sched_barrier(0);
  hP0 = hA[aBase];       hP1 = hA[aBase + 1];
  hP2 = hA[aBase + 128]; hP3 = hA[aBase + 129];
  asm volatile("s_waitcnt vmcnt(4)" ::: "memory");   // own B(0)x2 landed
  __builtin_amdgcn_s_barrier();                      // all waves' B(0) landed
  __builtin_amdgcn_sched_barrier(0);

#pragma unroll 2
  for (int kb = 0; kb < NST; ++kb) {
    const int slot = (kb & 1) * 8192, nslot = slot ^ 8192;
    const bool more = (kb + 1 < NST);
    if (more) {
      async16(gB + (size_t)((kb + 1) * 2) * 1024,     smem + nslot + dB0o);
      async16(gB + (size_t)((kb + 1) * 2 + 1) * 1024, smem + nslot + dB1o);
      __builtin_amdgcn_sched_barrier(0);             // B before A loads
      const size_t ai = aBase + (size_t)((kb + 1) * 2) * 128;
      if (kb & 1) {
        hP0 = hA[ai];       hP1 = hA[ai + 1];
        hP2 = hA[ai + 128]; hP3 = hA[ai + 129];
      } else {
        hQ0 = hA[ai];       hQ1 = hA[ai + 1];
        hQ2 = hA[ai + 128]; hQ3 = hA[ai + 129];
      }
      __builtin_amdgcn_sched_barrier(0);
    }
    // quant A(kb) from parity regs -> operands, MFMA vs B slot
    {
      const uint4 h0 = (kb & 1) ? hQ0 : hP0;
      const uint4 h1 = (kb & 1) ? hQ1 : hP1;
      const uint4 h2 = (kb & 1) ? hQ2 : hP2;
      const uint4 h3 = (kb & 1) ? hQ3 : hP3;
      uint4 oa, ob;
      oa.x = q4h(h0.x, h0.y, s2, m2); oa.y = q4h(h0.z, h0.w, s2, m2);
      oa.z = q4h(h1.x, h1.y, s2, m2); oa.w = q4h(h1.z, h1.w, s2, m2);
      ob.x = q4h(h2.x, h2.y, s2, m2); ob.y = q4h(h2.z, h2.w, s2, m2);
      ob.z = q4h(h3.x, h3.y, s2, m2); ob.w = q4h(h3.z, h3.w, s2, m2);
      const v4i af0 = *(const v4i*)&oa;    // kc0 operand
      const v4i af1 = *(const v4i*)&ob;    // kc1 operand
      v4i b0 = *(const v4i*)(smem + slot + rdo);
      v4i b1 = *(const v4i*)(smem + slot + 1024 + rdo);
      v4i b2 = *(const v4i*)(smem + slot + 2048 + rdo);
      v4i b3 = *(const v4i*)(smem + slot + 3072 + rdo);
      __builtin_amdgcn_s_setprio(1);
      acc[0] = __builtin_amdgcn_mfma_i32_32x32x32_i8(af0, b0, acc[0], 0, 0, 0);
      acc[1] = __builtin_amdgcn_mfma_i32_32x32x32_i8(af0, b1, acc[1], 0, 0, 0);
      acc[2] = __builtin_amdgcn_mfma_i32_32x32x32_i8(af0, b2, acc[2], 0, 0, 0);
      acc[3] = __builtin_amdgcn_mfma_i32_32x32x32_i8(af0, b3, acc[3], 0, 0, 0);
      __builtin_amdgcn_s_setprio(0);
      b0 = *(const v4i*)(smem + slot + 4096 + rdo);
      b1 = *(const v4i*)(smem + slot + 5120 + rdo);
      b2 = *(const v4i*)(smem + slot + 6144 + rdo);
      b3 = *(const v4i*)(smem + slot + 7168 + rdo);
      __builtin_amdgcn_s_setprio(1);
      acc[0] = __builtin_amdgcn_mfma_i32_32x32x32_i8(af1, b0, acc[0], 0, 0, 0);
      acc[1] = __builtin_amdgcn_mfma_i32_32x32x32_i8(af1, b1, acc[1], 0, 0, 0);
      acc[2] = __builtin_amdgcn_mfma_i32_32x32x32_i8(af1, b2, acc[2], 0, 0, 0);
      acc[3] = __builtin_amdgcn_mfma_i32_32x32x32_i8(af1, b3, acc[3], 0, 0, 0);
      __builtin_amdgcn_s_setprio(0);
    }
    if (more) {
      asm volatile("s_waitcnt vmcnt(4)" ::: "memory");  // own B(kb+1)x2 landed
      __builtin_amdgcn_s_barrier();
      __builtin_amdgcn_sched_barrier(0);
    }
  }

  // epilogue: out f32 row-major [8192,1024]; wave owns 32 rows x 128 cols
  const int cl = lane & 31;
  const int rbase = 4 * (lane >> 5);
  float bsc[4], bv[4];
  int colv[4];
#pragma unroll
  for (int nf = 0; nf < 4; ++nf) {
    colv[nf] = n0 + nf * 32 + cl;
    bsc[nf] = fmaxf(cmax[colv[nf]], EPSQ) * (1.0f / 127.0f) * asc;
    bv[nf] = bias[colv[nf]];
  }
#pragma unroll
  for (int g = 0; g < 4; ++g)
#pragma unroll
    for (int r2 = 0; r2 < 4; ++r2) {
      const int row = m0 + wave * 32 + g * 8 + r2 + rbase;
#pragma unroll
      for (int nf = 0; nf < 4; ++nf)
        out[(size_t)row * 1024 + colv[nf]] =
            (float)acc[nf][g * 4 + r2] * bsc[nf] + bv[nf];
    }
}

extern "C" void kernel_launch(void* const* d_in, const int* in_sizes, int n_in,
                              void* d_out, int out_size, void* d_ws, size_t ws_size,
                              hipStream_t stream) {
  const float* x  = (const float*)d_in[0];   // [8192,1024]
  const float* mk = (const float*)d_in[1];   // [8192]
  const float* W1 = (const float*)d_in[2];   // [1024,4096]
  const float* b1 = (const float*)d_in[3];   // [4096]
  const float* W2 = (const float*)d_in[4];   // [4096,1024]
  const float* b2 = (const float*)d_in[5];   // [1024]
  float* out = (float*)d_out;                // [8192,1024]

  float* scG   = (float*)d_ws;               // [8]
  float* pmaxX = scG + 8;                    // [1024]
  float* pmaxH = pmaxX + 1024;               // [2048] (1024 used)
  float* pcm1  = pmaxH + 2048;               // [16*4096]
  float* pcm2  = pcm1 + 65536;               // [64*1024]
  float* cm1   = pcm2 + 65536;               // [4096]
  float* cm2   = cm1 + 4096;                 // [1024]
  int8_t* qx  = (int8_t*)(cm2 + 1024);           // 8 MiB  frag order
  int8_t* qw1 = qx  + (size_t)8192 * 1024;       // 4 MiB  frag order [4096 n][1024 k]
  int8_t* qw2 = qw1 + (size_t)4096 * 1024;       // 4 MiB  frag order [1024 n][4096 k]
  unsigned short* h = (unsigned short*)(qw2 + (size_t)1024 * 4096);  // 64 MiB fp16 frag order

  k_stats<<<1152, 256, 0, stream>>>(x, mk, W1, W2, pmaxX, pcm1, pcm2);
  k_quant<<<2560, 256, 0, stream>>>(x, W1, W2, pmaxX, pcm1, pcm2,
                                    qx, qw1, qw2, cm1, cm2, scG);
  gemm1<<<1024, 512, 0, stream>>>(qx, qw1, scG, cm1, b1, mk, h, pmaxH);
  gemm2<<<512, 256, 0, stream>>>(h, qw2, pmaxH, cm2, b2, out);
}